// Round 9
// baseline (45.583 us; speedup 1.0000x reference)
//
#include <hip/hip_runtime.h>

// Depthwise conv1d along L, K=25, replicate padding, + scalar bias.
// x: [B=32, L=2048, C=512] f32 -> out same shape.
//
// R8: clean halo retest. R7's TL=256 x 32ch introduced 8-way LDS bank
// conflicts (128B rows). Keep R6's conflict-free 256B row segments
// (QCH=64, c4 spans all 32 banks) and shrink the halo by doubling TL:
// TL=256 x QCH=64, halo 280/256 = 1.09x, LDS 71.7KB -> 2 blocks/CU.
// Compute iterates two 128-row halves (same acc footprint as R6).

typedef float f32x4 __attribute__((ext_vector_type(4)));

constexpr int K     = 25;
constexpr int HALF  = 12;
constexpr int BB    = 32;
constexpr int LL    = 2048;
constexpr int CC    = 512;
constexpr int QCH   = 64;               // channels per block
constexpr int QC4   = QCH / 4;          // 16 f32x4 per row segment
constexpr int TL    = 256;              // L-outputs per block
constexpr int NROWS = TL + K - 1;       // 280 staged rows
constexpr int NQUAD = (NROWS + 3) / 4;  // 70 gll16 groups (1KB = 4 rows each)
constexpr int NQ    = CC / QCH;         // 8
constexpr int NT    = LL / TL;          // 8
constexpr int NBLK  = BB * NQ * NT;     // 2048

__device__ inline void gll16(const float* g, float* l) {
    __builtin_amdgcn_global_load_lds(
        (const __attribute__((address_space(1))) void*)g,
        (__attribute__((address_space(3))) void*)l, 16, 0, 0);
}

__global__ __launch_bounds__(256) void conv1d_dw_kernel(
    const float* __restrict__ x,
    const float* __restrict__ w,
    const float* __restrict__ bias_p,
    float* __restrict__ out)
{
    __shared__ float lds[NROWS * QCH];      // 71680 B

    // XCD-aware swizzle; adjacent lbid = adjacent L-tile of same (b,qc)
    // so halo lines are L2-warm on the same XCD.
    const int bid  = blockIdx.x;
    const int lbid = (bid & 7) * (NBLK >> 3) + (bid >> 3);

    const int lt = lbid & (NT - 1);          // 0..7   L-tile
    const int qc = (lbid >> 3) & (NQ - 1);   // 0..7   channel slice
    const int b  = lbid >> 6;                // 0..31

    const int tid  = threadIdx.x;
    const int wv   = tid >> 6;               // 0..3
    const int lane = tid & 63;

    const int Lbase = lt * TL;
    const float* xq = x   + (size_t)b * LL * CC + qc * QCH;
    float*       oq = out + (size_t)b * LL * CC + qc * QCH;

    // ---- stage 280 rows x 256 B (70 x 1KB gll16 per block) ----
#pragma unroll
    for (int i = 0; i < 18; ++i) {
        const int qd = wv + 4 * i;                    // wave-uniform
        if (qd < NQUAD) {
            const int v  = qd * 4 + (lane >> 4);      // staged row 0..279
            const int li = max(0, min(LL - 1, Lbase + v - HALF));
            gll16(xq + (size_t)li * CC + (lane & 15) * 4,
                  lds + (size_t)qd * 4 * QCH);        // linear dest, +lane*16
        }
    }

    float wr[K];
#pragma unroll
    for (int k = 0; k < K; ++k) wr[k] = w[k];         // wave-uniform -> SGPR
    const float bias = bias_p[0];

    __syncthreads();                                  // vmcnt(0) drain here

    // ---- compute: two 128-output halves; thread = (lgrp, c4) ----
    const int lgrp = tid >> 4;               // 0..15
    const int c4   = tid & 15;               // f32x4 column

    const f32x4* ldsv = reinterpret_cast<const f32x4*>(lds);
#pragma unroll
    for (int h = 0; h < 2; ++h) {
        f32x4 acc[8];
#pragma unroll
        for (int j = 0; j < 8; ++j) acc[j] = (f32x4){bias, bias, bias, bias};

        const int rbase = h * 128 + lgrp * 8;
#pragma unroll
        for (int rr = 0; rr < 32; ++rr) {
            const f32x4 rv = ldsv[(size_t)(rbase + rr) * QC4 + c4];
#pragma unroll
            for (int j = 0; j < 8; ++j) {
                const int k = rr - j;        // compile-time per (rr,j)
                if (k >= 0 && k < K) acc[j] += wr[k] * rv;
            }
        }

        const int l0 = Lbase + h * 128 + lgrp * 8;
#pragma unroll
        for (int j = 0; j < 8; ++j)
            __builtin_nontemporal_store(acc[j],
                reinterpret_cast<f32x4*>(oq + (size_t)(l0 + j) * CC) + c4);
    }
}

extern "C" void kernel_launch(void* const* d_in, const int* in_sizes, int n_in,
                              void* d_out, int out_size, void* d_ws, size_t ws_size,
                              hipStream_t stream) {
    const float* x  = (const float*)d_in[0];
    const float* w  = (const float*)d_in[1];
    const float* bp = (const float*)d_in[2];
    float* out      = (float*)d_out;

    conv1d_dw_kernel<<<NBLK, 256, 0, stream>>>(x, w, bp, out);
}

// Round 10
// 43.636 us; speedup vs baseline: 1.0446x; 1.0446x over previous
//
#include <hip/hip_runtime.h>

// Depthwise conv1d along L, K=25, replicate padding, + scalar bias.
// x: [B=32, L=2048, C=512] f32 -> out same shape.
//
// R9 = R6 resubmitted (best config; R7/R8 tested the remaining levers and
// both regressed). TL=128 outputs x 64 channels per block: conflict-free
// 256B row segments, halo 152/128 = 1.19x, LDS 38.9 KB -> 4 blocks/CU.
// Stage-all via global_load_lds w=16 -> syncthreads -> compute from LDS ->
// NT stores. 43.6 us = 6.15 TB/s app-level = 97.8% of measured copy ceiling.
//
// Design-space results (bench us): R4 TL=32/56KB/2blk: 48.1; R5 ring+vmcnt
// pipeline: 49.2 (null); R6: 43.6; R7 TL=256x32ch: 44.1 (8-way LDS bank
// conflicts); R8 TL=256x64ch/72KB/2blk: 45.6 (occupancy loss; FETCH
// unchanged -> halo is L2/L3-absorbed, not HBM traffic).

typedef float f32x4 __attribute__((ext_vector_type(4)));

constexpr int K     = 25;
constexpr int HALF  = 12;
constexpr int BB    = 32;
constexpr int LL    = 2048;
constexpr int CC    = 512;
constexpr int QCH   = 64;               // channels per block
constexpr int QC4   = QCH / 4;          // 16 f32x4 per row segment
constexpr int TL    = 128;              // L-outputs per block
constexpr int NROWS = TL + K - 1;       // 152 staged rows
constexpr int NQUAD = NROWS / 4;        // 38 gll-quads (1KB each)
constexpr int NQ    = CC / QCH;         // 8
constexpr int NT    = LL / TL;          // 16
constexpr int NBLK  = BB * NQ * NT;     // 4096

__device__ inline void gll16(const float* g, float* l) {
    __builtin_amdgcn_global_load_lds(
        (const __attribute__((address_space(1))) void*)g,
        (__attribute__((address_space(3))) void*)l, 16, 0, 0);
}

__global__ __launch_bounds__(256) void conv1d_dw_kernel(
    const float* __restrict__ x,
    const float* __restrict__ w,
    const float* __restrict__ bias_p,
    float* __restrict__ out)
{
    __shared__ float lds[NROWS * QCH];      // 38912 B

    // XCD-aware swizzle; adjacent lbid = adjacent L-tile of same (b,qc)
    // so halo lines are L2-warm on the same XCD.
    const int bid  = blockIdx.x;
    const int lbid = (bid & 7) * (NBLK >> 3) + (bid >> 3);

    const int lt = lbid & (NT - 1);          // 0..15  L-tile
    const int qc = (lbid >> 4) & (NQ - 1);   // 0..7   channel slice
    const int b  = lbid >> 7;                // 0..31

    const int tid  = threadIdx.x;
    const int wv   = tid >> 6;               // 0..3
    const int lane = tid & 63;

    const int Lbase = lt * TL;
    const float* xq = x   + (size_t)b * LL * CC + qc * QCH;
    float*       oq = out + (size_t)b * LL * CC + qc * QCH;

    // ---- stage 152 rows x 256 B (38 x 1KB gll16 per block) ----
#pragma unroll
    for (int i = 0; i < 10; ++i) {
        const int qd = wv + 4 * i;                    // wave-uniform
        if (qd < NQUAD) {
            const int v  = qd * 4 + (lane >> 4);      // staged row 0..151
            const int li = max(0, min(LL - 1, Lbase + v - HALF));
            gll16(xq + (size_t)li * CC + (lane & 15) * 4,
                  lds + (size_t)qd * 4 * QCH);        // linear dest, +lane*16
        }
    }

    float wr[K];
#pragma unroll
    for (int k = 0; k < K; ++k) wr[k] = w[k];         // wave-uniform -> SGPR
    const float bias = bias_p[0];

    __syncthreads();                                  // vmcnt(0) drain here

    // ---- compute: thread = (lgrp = tid>>4 -> 8 l-outputs, c4 = tid&15) ----
    const int lgrp = tid >> 4;               // 0..15
    const int c4   = tid & 15;               // f32x4 column

    f32x4 acc[8];
#pragma unroll
    for (int j = 0; j < 8; ++j) acc[j] = (f32x4){bias, bias, bias, bias};

    const f32x4* ldsv = reinterpret_cast<const f32x4*>(lds);
#pragma unroll
    for (int rr = 0; rr < 32; ++rr) {
        const f32x4 rv = ldsv[(size_t)(lgrp * 8 + rr) * QC4 + c4];
#pragma unroll
        for (int j = 0; j < 8; ++j) {
            const int k = rr - j;            // compile-time per (rr,j)
            if (k >= 0 && k < K) acc[j] += wr[k] * rv;
        }
    }

    const int l0 = Lbase + lgrp * 8;
#pragma unroll
    for (int j = 0; j < 8; ++j)
        __builtin_nontemporal_store(acc[j],
            reinterpret_cast<f32x4*>(oq + (size_t)(l0 + j) * CC) + c4);
}

extern "C" void kernel_launch(void* const* d_in, const int* in_sizes, int n_in,
                              void* d_out, int out_size, void* d_ws, size_t ws_size,
                              hipStream_t stream) {
    const float* x  = (const float*)d_in[0];
    const float* w  = (const float*)d_in[1];
    const float* bp = (const float*)d_in[2];
    float* out      = (float*)d_out;

    conv1d_dw_kernel<<<NBLK, 256, 0, stream>>>(x, w, bp, out);
}